// Round 5
// baseline (2235.132 us; speedup 1.0000x reference)
//
#include <hip/hip_runtime.h>
#include <math.h>

#define B_      4
#define F_BINS  128
#define T_FULL  16384
#define NW      8
#define KF      33
#define KT      129

// conv tile geometry
#define TT      192                // output t per block (3 fr x 16 x 4 waves)
#define ROWS    324                // TT + 132 halo
#define PITCH   56                 // ushort pitch for 48 f cols

typedef __attribute__((ext_vector_type(8))) short short8;
typedef __attribute__((ext_vector_type(4))) float f32x4;
typedef uint uint4a16 __attribute__((ext_vector_type(4), aligned(16)));

union ABFrag { uint4a16 u; short8 v; };

__device__ __forceinline__ ushort f2bf(float v) {
  unsigned u = __float_as_uint(v);
  unsigned r = (u + 0x7FFFu + ((u >> 16) & 1u)) >> 16;
  return (ushort)r;
}

__device__ __forceinline__ short8 load_a16(const ushort* p) {
  ABFrag f; f.u = *(const uint4a16*)p; return f.v;
}

// ---------------------------------------------------------------------------
// prep_w: fp-shifted, zero-padded bf16 weights
//   wq[oct 4][fp 4][ch 16][dt 132][d2i 48] = wav[ch][df = d2i - 8 - fp][dt]
//   (zero outside df in [0,33), dt in [0,129))
//   fp+4 / fp+8 / fp+12 planes are derived in-register from this layout.
// ---------------------------------------------------------------------------
__global__ __launch_bounds__(256) void prep_w(
    const float* __restrict__ wr, const float* __restrict__ wi,
    ushort* __restrict__ wq) {
  int idx = blockIdx.x * 256 + threadIdx.x;      // 4*4*16*132*48 = 1622016
  int d2i = idx % 48;
  int dt  = (idx / 48) % 132;
  int ch  = (idx / (48 * 132)) % 16;
  int fp  = (idx / (48 * 132 * 16)) % 4;
  int oct = idx / (48 * 132 * 16 * 4);
  int df  = d2i - 8 - fp;
  float v = 0.f;
  if (df >= 0 && df < KF && dt < KT) {
    const float* src = (ch < 8) ? wr : wi;
    v = src[(((size_t)oct * 8 + (ch & 7)) * KF + df) * KT + dt];
  }
  wq[idx] = f2bf(v);
}

// ---------------------------------------------------------------------------
// prep_x: bf16 transposed pyramid  xTj[b][T_j][128f]  for j=0..3
// ---------------------------------------------------------------------------
__global__ __launch_bounds__(256) void prep_x(
    const float* __restrict__ x,
    ushort* __restrict__ xT0, ushort* __restrict__ xT1,
    ushort* __restrict__ xT2, ushort* __restrict__ xT3) {
  __shared__ float lt[128 * 65];
  const int b  = blockIdx.y;
  const int t0 = blockIdx.x * 64;
  const int tid = threadIdx.x;
  const int wv = tid >> 6, lane = tid & 63;
#pragma unroll
  for (int rep = 0; rep < 32; ++rep) {
    int f = rep * 4 + wv;
    lt[f * 65 + lane] = x[((size_t)b * 128 + f) * T_FULL + t0 + lane];
  }
  __syncthreads();
  ushort* dst[4] = {xT0, xT1, xT2, xT3};
  const int Ts[4] = {16384, 8192, 4096, 2048};
  for (int lvl = 0; lvl < 4; ++lvl) {
    int nt = 64 >> lvl, w = 1 << lvl;
    float inv = 1.f / (float)w;
    int tasks = nt * 16;
    for (int i = tid; i < tasks; i += 256) {
      int tl = i >> 4, fc = i & 15;
      __align__(16) ushort vs[8];
#pragma unroll
      for (int e = 0; e < 8; ++e) {
        float a = 0.f;
        for (int m = 0; m < w; ++m) a += lt[(fc * 8 + e) * 65 + tl * w + m];
        vs[e] = f2bf(a * inv);
      }
      ushort* pdst = dst[lvl] + ((size_t)b * Ts[lvl] + (t0 >> lvl) + tl) * 128 + fc * 8;
      *(uint4*)pdst = *(const uint4*)vs;
    }
  }
}

// ---------------------------------------------------------------------------
// conv_mfma: one octave. Block = 256 thr = 4 waves; tile = 16 f_out x 192 t.
// MFMA 16x16x32_bf16: M=ch16 (A=weights), N=pos16 (B=x), K=(4 dt x 8 df).
// Per fp-iter computes 4 output-f planes {fp, fp+4, fp+8, fp+12}:
//   aA0: F[s+1] ; aB0: G[s] ; aA1: F[s] ; aB1: G[s-1]
// (G = d2-shift-by-4 register concat). A-loads double-buffered across c.
// LDS 35.4 KB -> 4 blocks/CU (16 waves) for cross-block overlap.
// ---------------------------------------------------------------------------
template<int WP, int OCT>
__global__ __launch_bounds__(256, 4) void conv_mfma(
    const ushort* __restrict__ xT, const ushort* __restrict__ wq,
    float* __restrict__ out, int Tj) {
  __shared__ ushort xt[ROWS * PITCH];
  const int tid = threadIdx.x;
  const int t0 = blockIdx.x * TT;
  const int f0 = blockIdx.y * 16;
  const int b  = blockIdx.z;

  // ---- stage transposed x tile: rows 0..323 (t = t0-64+row), cols f0-16+[0,48) ----
  for (int i = tid; i < ROWS * 6; i += 256) {
    int row = i / 6, fc = i % 6;
    int t = t0 - 64 + row;
    int f = f0 - 16 + fc * 8;             // chunk fully in or fully out of range
    uint4 v = make_uint4(0u, 0u, 0u, 0u);
    if (t >= 0 && t < Tj && f >= 0 && f < 128)
      v = *(const uint4*)(xT + ((size_t)b * Tj + t) * 128 + f);
    *(uint4*)&xt[row * PITCH + fc * 8] = v;
  }
  __syncthreads();

  const int wave = tid >> 6, lane = tid & 63;
  const int p = lane & 15;                 // A-row = channel sel, B-col = position
  const int g = lane >> 4;                 // k-group (dt sub-index)

  const float invw = 1.f / (float)WP;

  for (int fp = 0; fp < 4; ++fp) {
    const ushort* wp = wq + ((((size_t)OCT * 4 + fp) * 16 + p) * 132 + g) * 48;
    int rb = (p + g) * PITCH + wave * (48 * PITCH);   // ushort offset in xt

    f32x4 aA0[3], aA1[3], aB0[3], aB1[3];
#pragma unroll
    for (int r = 0; r < 3; ++r) {
      f32x4 z = {0.f, 0.f, 0.f, 0.f};
      aA0[r] = z; aA1[r] = z; aB0[r] = z; aB1[r] = z;
    }

    short8 Fa[6], Fb[6];

    auto load6 = [](short8 (&F)[6], const ushort* ptr) {
#pragma unroll
      for (int u = 0; u < 6; ++u) F[u] = load_a16(ptr + 8 * u);
    };

    auto body = [&](short8 (&F)[6], int rbase) {
      short8 G[5];
#pragma unroll
      for (int u = 0; u < 5; ++u)
        G[u] = __builtin_shufflevector(F[u], F[u + 1], 4, 5, 6, 7, 8, 9, 10, 11);
      __builtin_amdgcn_s_setprio(1);
#pragma unroll
      for (int s = 0; s <= 5; ++s) {
#pragma unroll
        for (int fr = 0; fr < 3; ++fr) {
          short8 bv = *(const short8*)&xt[rbase + fr * (16 * PITCH) + s * 8];
          if (s < 5) {
            aA0[fr] = __builtin_amdgcn_mfma_f32_16x16x32_bf16(F[s + 1], bv, aA0[fr], 0, 0, 0);
            aB0[fr] = __builtin_amdgcn_mfma_f32_16x16x32_bf16(G[s],     bv, aB0[fr], 0, 0, 0);
          }
          if (s > 0) {
            aA1[fr] = __builtin_amdgcn_mfma_f32_16x16x32_bf16(F[s],     bv, aA1[fr], 0, 0, 0);
            aB1[fr] = __builtin_amdgcn_mfma_f32_16x16x32_bf16(G[s - 1], bv, aB1[fr], 0, 0, 0);
          }
        }
      }
      __builtin_amdgcn_s_setprio(0);
    };

    // software-pipelined c-loop: 33 iterations = 16 x 2 + 1
    load6(Fa, wp);
#pragma unroll 1
    for (int cc = 0; cc < 16; ++cc) {
      load6(Fb, wp + 192);          // c = 2cc+1
      body(Fa, rb);                 // c = 2cc
      load6(Fa, wp + 384);          // c = 2cc+2 (cc=15 -> c=32)
      body(Fb, rb + 224);           // c = 2cc+1
      wp += 384; rb += 448;
    }
    body(Fa, rb);                   // c = 32

    // ---- epilogue: modulus (lane^32 pairs re/im) + avg-pool via butterfly ----
    auto epi = [&](f32x4 (&acc)[3], int fo) {
#pragma unroll
      for (int fr = 0; fr < 3; ++fr) {
        const int tbase = t0 + 16 * (3 * wave + fr);
#pragma unroll
        for (int r = 0; r < 4; ++r) {
          float a = acc[fr][r];
          float o = __shfl_xor(a, 32);
          float m = sqrtf(a * a + o * o);
#pragma unroll
          for (int mask = WP / 2; mask >= 1; mask >>= 1)
            m += __shfl_xor(m, mask);
          if (((p & (WP - 1)) == 0) && g < 2) {
            int ch = 4 * g + r;
            int tcol = (tbase + p) / WP;
            if (tcol < 1024)
              out[(((size_t)b * 32 + OCT * 8 + ch) * 128 + fo) * 1024 + tcol] = m * invw;
          }
        }
      }
    };
    epi(aA0, f0 + fp);
    epi(aB0, f0 + fp + 4);
    epi(aA1, f0 + fp + 8);
    epi(aB1, f0 + fp + 12);
  }
}

// ---------------------------------------------------------------------------
extern "C" void kernel_launch(void* const* d_in, const int* in_sizes, int n_in,
                              void* d_out, int out_size, void* d_ws, size_t ws_size,
                              hipStream_t stream) {
  const float* x  = (const float*)d_in[0];
  const float* wr = (const float*)d_in[1];
  const float* wi = (const float*)d_in[2];
  float* out = (float*)d_out;

  ushort* xT0 = (ushort*)d_ws;                       // 4*16384*128
  ushort* xT1 = xT0 + (size_t)4 * 16384 * 128;       // 4*8192*128
  ushort* xT2 = xT1 + (size_t)4 * 8192 * 128;        // 4*4096*128
  ushort* xT3 = xT2 + (size_t)4 * 4096 * 128;        // 4*2048*128
  ushort* wq  = xT3 + (size_t)4 * 2048 * 128;        // 1622016

  prep_w<<<1622016 / 256, 256, 0, stream>>>(wr, wi, wq);
  prep_x<<<dim3(T_FULL / 64, B_), 256, 0, stream>>>(x, xT0, xT1, xT2, xT3);

  conv_mfma<16, 0><<<dim3((16384 + TT - 1) / TT, 8, 4), 256, 0, stream>>>(xT0, wq, out, 16384);
  conv_mfma< 8, 1><<<dim3(( 8192 + TT - 1) / TT, 8, 4), 256, 0, stream>>>(xT1, wq, out, 8192);
  conv_mfma< 4, 2><<<dim3(( 4096 + TT - 1) / TT, 8, 4), 256, 0, stream>>>(xT2, wq, out, 4096);
  conv_mfma< 2, 3><<<dim3(( 2048 + TT - 1) / TT, 8, 4), 256, 0, stream>>>(xT3, wq, out, 2048);
}

// Round 6
// 1834.472 us; speedup vs baseline: 1.2184x; 1.2184x over previous
//
#include <hip/hip_runtime.h>
#include <math.h>

#define B_      4
#define F_BINS  128
#define T_FULL  16384
#define NW      8
#define KF      33
#define KT      129

// conv tile geometry: f-tile 32 planes x TT 128 t per block
#define TT      128
#define ROWS    260                // TT + 132 halo
#define PITCH   72                 // ushort pitch for 64 f cols (16B-aligned rows)
#define DTP     136                // padded dt rows in wq (129 + pad for prefetch)
#define D2      48                 // padded d2 window

typedef __attribute__((ext_vector_type(8))) short short8;
typedef __attribute__((ext_vector_type(4))) float f32x4;
typedef uint uint4a16 __attribute__((ext_vector_type(4), aligned(16)));

union ABFrag { uint4a16 u; short8 v; };

__device__ __forceinline__ ushort f2bf(float v) {
  unsigned u = __float_as_uint(v);
  unsigned r = (u + 0x7FFFu + ((u >> 16) & 1u)) >> 16;
  return (ushort)r;
}

__device__ __forceinline__ short8 load_a16(const ushort* p) {
  ABFrag f; f.u = *(const uint4a16*)p; return f.v;
}

__device__ __forceinline__ short8 mkG(short8 a, short8 b) {
  return __builtin_shufflevector(a, b, 4, 5, 6, 7, 8, 9, 10, 11);
}

// ---------------------------------------------------------------------------
// prep_w: gamma-shifted, zero-padded bf16 weights
//   wq[oct 4][gam 4][ch 16][dt 136][d2 48] = wav[ch][df = d2 - 4 - gam][dt]
//   zero outside df in [0,33), dt in [0,129). Planes fo = f0+gam+4k share
//   this block via register-window shifts (F/G fragments).
// ---------------------------------------------------------------------------
__global__ __launch_bounds__(256) void prep_w(
    const float* __restrict__ wr, const float* __restrict__ wi,
    ushort* __restrict__ wq) {
  int idx = blockIdx.x * 256 + threadIdx.x;      // 4*4*16*136*48 = 1671168
  int d2  = idx % D2;
  int dt  = (idx / D2) % DTP;
  int ch  = (idx / (D2 * DTP)) % 16;
  int gam = (idx / (D2 * DTP * 16)) % 4;
  int oct = idx / (D2 * DTP * 16 * 4);
  int df  = d2 - 4 - gam;
  float v = 0.f;
  if (df >= 0 && df < KF && dt < KT) {
    const float* src = (ch < 8) ? wr : wi;
    v = src[(((size_t)oct * 8 + (ch & 7)) * KF + df) * KT + dt];
  }
  wq[idx] = f2bf(v);
}

// ---------------------------------------------------------------------------
// prep_x: bf16 transposed pyramid  xTj[b][T_j][128f]  for j=0..3
// ---------------------------------------------------------------------------
__global__ __launch_bounds__(256) void prep_x(
    const float* __restrict__ x,
    ushort* __restrict__ xT0, ushort* __restrict__ xT1,
    ushort* __restrict__ xT2, ushort* __restrict__ xT3) {
  __shared__ float lt[128 * 65];
  const int b  = blockIdx.y;
  const int t0 = blockIdx.x * 64;
  const int tid = threadIdx.x;
  const int wv = tid >> 6, lane = tid & 63;
#pragma unroll
  for (int rep = 0; rep < 32; ++rep) {
    int f = rep * 4 + wv;
    lt[f * 65 + lane] = x[((size_t)b * 128 + f) * T_FULL + t0 + lane];
  }
  __syncthreads();
  ushort* dst[4] = {xT0, xT1, xT2, xT3};
  const int Ts[4] = {16384, 8192, 4096, 2048};
  for (int lvl = 0; lvl < 4; ++lvl) {
    int nt = 64 >> lvl, w = 1 << lvl;
    float inv = 1.f / (float)w;
    int tasks = nt * 16;
    for (int i = tid; i < tasks; i += 256) {
      int tl = i >> 4, fc = i & 15;
      __align__(16) ushort vs[8];
#pragma unroll
      for (int e = 0; e < 8; ++e) {
        float a = 0.f;
        for (int m = 0; m < w; ++m) a += lt[(fc * 8 + e) * 65 + tl * w + m];
        vs[e] = f2bf(a * inv);
      }
      ushort* pdst = dst[lvl] + ((size_t)b * Ts[lvl] + (t0 >> lvl) + tl) * 128 + fc * 8;
      *(uint4*)pdst = *(const uint4*)vs;
    }
  }
}

// ---------------------------------------------------------------------------
// conv_mfma: one octave. Block = 256 thr = 4 waves; tile = 32 f_out x 128 t.
// MFMA 16x16x32_bf16: M=ch16 (A=weights), N=pos16 (B=x), K=(4 dt x 8 d2).
// Per gamma-iter computes 8 output-f planes fo = f0 + gamma + 4k (k=0..7):
//   odd  k: A = F[s - (k-1)/2]
//   even k: A = G[s - k/2]      (G[u] = 4-shift concat of F[u],F[u+1])
// with per-plane active s in [s_lo(k), s_lo(k)+4], s_lo = {0,0,1,1,2,2,3,3}.
// Each B ds_read_b128 feeds up to 8 MFMAs -> LDS pipe at ~1/3 of matrix.
// F/G rotate in place: next-c fragment u is loaded right after last use.
// ---------------------------------------------------------------------------
template<int WP, int OCT>
__global__ __launch_bounds__(256, 3) void conv_mfma(
    const ushort* __restrict__ xT, const ushort* __restrict__ wq,
    float* __restrict__ out, int Tj) {
  __shared__ ushort xt[ROWS * PITCH];
  const int tid = threadIdx.x;
  const int t0 = blockIdx.x * TT;
  const int f0 = blockIdx.y * 32;
  const int b  = blockIdx.z;

  // ---- stage transposed x tile: rows 0..259 (t = t0-64+row), cols f0-16+[0,64) ----
  for (int i = tid; i < ROWS * 8; i += 256) {
    int row = i >> 3, fc = i & 7;
    int t = t0 - 64 + row;
    int f = f0 - 16 + fc * 8;             // chunk fully in or fully out of range
    uint4 v = make_uint4(0u, 0u, 0u, 0u);
    if (t >= 0 && t < Tj && f >= 0 && f < 128)
      v = *(const uint4*)(xT + ((size_t)b * Tj + t) * 128 + f);
    *(uint4*)&xt[row * PITCH + fc * 8] = v;
  }
  __syncthreads();

  const int wave = tid >> 6, lane = tid & 63;
  const int p = lane & 15;                 // A-row = channel sel, B-col = position
  const int g = lane >> 4;                 // k-group (dt sub-index)

  const float invw = 1.f / (float)WP;

  for (int gamma = 0; gamma < 4; ++gamma) {
    const ushort* wbase = wq + ((((size_t)OCT * 4 + gamma) * 16 + p) * DTP + g) * D2;
    const ushort* wp = wbase + 4 * D2;     // in-body loads fetch c+1
    int rb = (p + g) * PITCH + wave * (32 * PITCH);

    f32x4 acc[8][2];
#pragma unroll
    for (int k = 0; k < 8; ++k)
#pragma unroll
      for (int r = 0; r < 2; ++r) { f32x4 z = {0.f, 0.f, 0.f, 0.f}; acc[k][r] = z; }

    short8 F[6], G[5];
#pragma unroll
    for (int u = 0; u < 6; ++u) F[u] = load_a16(wbase + 8 * u);
    G[0] = mkG(F[0], F[1]);
    G[1] = mkG(F[1], F[2]);

#pragma unroll 1
    for (int c = 0; c < 33; ++c) {
      __builtin_amdgcn_s_setprio(1);
      const int SLO[8] = {0, 0, 1, 1, 2, 2, 3, 3};
#pragma unroll
      for (int s = 0; s < 8; ++s) {
        if (s == 0) G[2] = mkG(F[2], F[3]);
        if (s == 1) G[3] = mkG(F[3], F[4]);
        if (s == 2) G[4] = mkG(F[4], F[5]);
        short8 bv0 = *(const short8*)&xt[rb + s * 8];
        short8 bv1 = *(const short8*)&xt[rb + 16 * PITCH + s * 8];
#pragma unroll
        for (int k = 0; k < 8; ++k) {
          if (s >= SLO[k] && s <= SLO[k] + 4) {
            const int idx = s - SLO[k];
            short8 a = (k & 1) ? F[idx] : G[idx];
            acc[k][0] = __builtin_amdgcn_mfma_f32_16x16x32_bf16(a, bv0, acc[k][0], 0, 0, 0);
            acc[k][1] = __builtin_amdgcn_mfma_f32_16x16x32_bf16(a, bv1, acc[k][1], 0, 0, 0);
          }
        }
        // in-place prefetch of next-c fragments (after last use this c)
        if (s >= 3) F[s - 3] = load_a16(wp + 8 * (s - 3));
        if (s == 6) G[0] = mkG(F[0], F[1]);   // next-c G
        if (s == 7) G[1] = mkG(F[1], F[2]);   // next-c G
      }
      F[5] = load_a16(wp + 40);
      __builtin_amdgcn_s_setprio(0);
      wp += 4 * D2;                // dt += 4
      rb += 4 * PITCH;             // row += 4
    }

    // ---- epilogue: modulus (lane^32 pairs re/im) + avg-pool via butterfly ----
#pragma unroll
    for (int k = 0; k < 8; ++k) {
      const int fo = f0 + gamma + 4 * k;
#pragma unroll
      for (int fr = 0; fr < 2; ++fr) {
        const int tbase = t0 + 32 * wave + 16 * fr;
#pragma unroll
        for (int r = 0; r < 4; ++r) {
          float a = acc[k][fr][r];
          float o = __shfl_xor(a, 32);
          float m = sqrtf(a * a + o * o);
#pragma unroll
          for (int mask = WP / 2; mask >= 1; mask >>= 1)
            m += __shfl_xor(m, mask);
          if (((p & (WP - 1)) == 0) && g < 2) {
            int ch = 4 * g + r;
            int tcol = (tbase + p) / WP;
            out[(((size_t)b * 32 + OCT * 8 + ch) * 128 + fo) * 1024 + tcol] = m * invw;
          }
        }
      }
    }
  }
}

// ---------------------------------------------------------------------------
extern "C" void kernel_launch(void* const* d_in, const int* in_sizes, int n_in,
                              void* d_out, int out_size, void* d_ws, size_t ws_size,
                              hipStream_t stream) {
  const float* x  = (const float*)d_in[0];
  const float* wr = (const float*)d_in[1];
  const float* wi = (const float*)d_in[2];
  float* out = (float*)d_out;

  ushort* xT0 = (ushort*)d_ws;                       // 4*16384*128
  ushort* xT1 = xT0 + (size_t)4 * 16384 * 128;       // 4*8192*128
  ushort* xT2 = xT1 + (size_t)4 * 8192 * 128;        // 4*4096*128
  ushort* xT3 = xT2 + (size_t)4 * 4096 * 128;        // 4*2048*128
  ushort* wq  = xT3 + (size_t)4 * 2048 * 128;        // 1671168

  prep_w<<<1671168 / 256, 256, 0, stream>>>(wr, wi, wq);
  prep_x<<<dim3(T_FULL / 64, B_), 256, 0, stream>>>(x, xT0, xT1, xT2, xT3);

  conv_mfma<16, 0><<<dim3(16384 / TT, 4, 4), 256, 0, stream>>>(xT0, wq, out, 16384);
  conv_mfma< 8, 1><<<dim3( 8192 / TT, 4, 4), 256, 0, stream>>>(xT1, wq, out, 8192);
  conv_mfma< 4, 2><<<dim3( 4096 / TT, 4, 4), 256, 0, stream>>>(xT2, wq, out, 4096);
  conv_mfma< 2, 3><<<dim3( 2048 / TT, 4, 4), 256, 0, stream>>>(xT3, wq, out, 2048);
}

// Round 7
// 1598.653 us; speedup vs baseline: 1.3981x; 1.1475x over previous
//
#include <hip/hip_runtime.h>
#include <math.h>

#define B_      4
#define F_BINS  128
#define T_FULL  16384
#define NW      8
#define KF      33
#define KT      129

// conv tile geometry: f-tile 32 planes x TT 128 t per block
#define TT      128
#define ROWS    260                // TT + 132 halo
#define PITCH   72                 // ushort pitch for 64 f cols (16B-aligned rows)
#define DTP     136                // padded dt rows in wq (129 + pad for prefetch)
#define D2      48                 // padded d2 window

typedef __attribute__((ext_vector_type(8))) short short8;
typedef __attribute__((ext_vector_type(4))) float f32x4;
typedef uint uint4a16 __attribute__((ext_vector_type(4), aligned(16)));

union ABFrag { uint4a16 u; short8 v; };

__device__ __forceinline__ ushort f2bf(float v) {
  unsigned u = __float_as_uint(v);
  unsigned r = (u + 0x7FFFu + ((u >> 16) & 1u)) >> 16;
  return (ushort)r;
}

__device__ __forceinline__ short8 load_a16(const ushort* p) {
  ABFrag f; f.u = *(const uint4a16*)p; return f.v;
}

__device__ __forceinline__ short8 mkG(short8 a, short8 b) {
  return __builtin_shufflevector(a, b, 4, 5, 6, 7, 8, 9, 10, 11);
}

// ---------------------------------------------------------------------------
// prep_w: gamma-shifted, zero-padded bf16 weights
//   wq[oct 4][gam 4][ch 16][dt 136][d2 48] = wav[ch][df = d2 - 4 - gam][dt]
//   zero outside df in [0,33), dt in [0,129). Planes fo = f0+gam+4k share
//   this block via register-window shifts (F/G fragments).
// ---------------------------------------------------------------------------
__global__ __launch_bounds__(256) void prep_w(
    const float* __restrict__ wr, const float* __restrict__ wi,
    ushort* __restrict__ wq) {
  int idx = blockIdx.x * 256 + threadIdx.x;      // 4*4*16*136*48 = 1671168
  int d2  = idx % D2;
  int dt  = (idx / D2) % DTP;
  int ch  = (idx / (D2 * DTP)) % 16;
  int gam = (idx / (D2 * DTP * 16)) % 4;
  int oct = idx / (D2 * DTP * 16 * 4);
  int df  = d2 - 4 - gam;
  float v = 0.f;
  if (df >= 0 && df < KF && dt < KT) {
    const float* src = (ch < 8) ? wr : wi;
    v = src[(((size_t)oct * 8 + (ch & 7)) * KF + df) * KT + dt];
  }
  wq[idx] = f2bf(v);
}

// ---------------------------------------------------------------------------
// prep_x: bf16 transposed pyramid  xTj[b][T_j][128f]  for j=0..3
// ---------------------------------------------------------------------------
__global__ __launch_bounds__(256) void prep_x(
    const float* __restrict__ x,
    ushort* __restrict__ xT0, ushort* __restrict__ xT1,
    ushort* __restrict__ xT2, ushort* __restrict__ xT3) {
  __shared__ float lt[128 * 65];
  const int b  = blockIdx.y;
  const int t0 = blockIdx.x * 64;
  const int tid = threadIdx.x;
  const int wv = tid >> 6, lane = tid & 63;
#pragma unroll
  for (int rep = 0; rep < 32; ++rep) {
    int f = rep * 4 + wv;
    lt[f * 65 + lane] = x[((size_t)b * 128 + f) * T_FULL + t0 + lane];
  }
  __syncthreads();
  ushort* dst[4] = {xT0, xT1, xT2, xT3};
  const int Ts[4] = {16384, 8192, 4096, 2048};
  for (int lvl = 0; lvl < 4; ++lvl) {
    int nt = 64 >> lvl, w = 1 << lvl;
    float inv = 1.f / (float)w;
    int tasks = nt * 16;
    for (int i = tid; i < tasks; i += 256) {
      int tl = i >> 4, fc = i & 15;
      __align__(16) ushort vs[8];
#pragma unroll
      for (int e = 0; e < 8; ++e) {
        float a = 0.f;
        for (int m = 0; m < w; ++m) a += lt[(fc * 8 + e) * 65 + tl * w + m];
        vs[e] = f2bf(a * inv);
      }
      ushort* pdst = dst[lvl] + ((size_t)b * Ts[lvl] + (t0 >> lvl) + tl) * 128 + fc * 8;
      *(uint4*)pdst = *(const uint4*)vs;
    }
  }
}

// ---------------------------------------------------------------------------
// conv_mfma: ALL octaves fused in one grid of 3840 equal-work blocks.
//   blocks [0,2048) oct0, [2048,3072) oct1, [3072,3584) oct2, [3584,3840) oct3
// Block = 256 thr = 4 waves; tile = 32 f_out x 128 t.
// MFMA 16x16x32_bf16: M=ch16 (A=weights), N=pos16 (B=x), K=(4 dt x 8 d2).
// Per gamma-iter computes 8 output-f planes fo = f0 + gamma + 4k (k=0..7):
//   odd  k: A = F[s - (k-1)/2] ; even k: A = G[s - k/2]
// with per-plane active s in [s_lo(k), s_lo(k)+4], s_lo = {0,0,1,1,2,2,3,3}.
// Epilogue deduped: lo lanes (g<2) finish r=0,1; hi lanes finish r=2,3.
// ---------------------------------------------------------------------------
__global__ __launch_bounds__(256, 3) void conv_mfma(
    const ushort* __restrict__ xT0, const ushort* __restrict__ xT1,
    const ushort* __restrict__ xT2, const ushort* __restrict__ xT3,
    const ushort* __restrict__ wq, float* __restrict__ out) {
  __shared__ ushort xt[ROWS * PITCH];
  const int tid = threadIdx.x;
  const int bx = blockIdx.x;

  int oct, local;
  if (bx < 2048)      { oct = 0; local = bx; }
  else if (bx < 3072) { oct = 1; local = bx - 2048; }
  else if (bx < 3584) { oct = 2; local = bx - 3072; }
  else                { oct = 3; local = bx - 3584; }
  const ushort* xT = (oct == 0) ? xT0 : (oct == 1) ? xT1 : (oct == 2) ? xT2 : xT3;
  const int Tj = T_FULL >> oct;
  const int lw = 4 - oct;                     // pool window = 1<<lw
  const int nxs = 7 - oct;                    // nx = 128>>oct
  const int tx = local & ((1 << nxs) - 1);
  const int rest = local >> nxs;
  const int t0 = tx * TT;
  const int f0 = (rest & 3) * 32;
  const int b  = rest >> 2;

  // ---- stage transposed x tile: rows 0..259 (t = t0-64+row), cols f0-16+[0,64) ----
  for (int i = tid; i < ROWS * 8; i += 256) {
    int row = i >> 3, fc = i & 7;
    int t = t0 - 64 + row;
    int f = f0 - 16 + fc * 8;             // chunk fully in or fully out of range
    uint4 v = make_uint4(0u, 0u, 0u, 0u);
    if (t >= 0 && t < Tj && f >= 0 && f < 128)
      v = *(const uint4*)(xT + ((size_t)b * Tj + t) * 128 + f);
    *(uint4*)&xt[row * PITCH + fc * 8] = v;
  }
  __syncthreads();

  const int wave = tid >> 6, lane = tid & 63;
  const int p = lane & 15;                 // A-row = channel sel, B-col = position
  const int g = lane >> 4;                 // k-group (dt sub-index)
  const int hi = (lane >= 32);
  const float invw = 1.0f / (float)(1 << lw);

  for (int gamma = 0; gamma < 4; ++gamma) {
    const ushort* wbase = wq + ((((size_t)oct * 4 + gamma) * 16 + p) * DTP + g) * D2;
    const ushort* wp = wbase + 4 * D2;     // in-body loads fetch c+1
    int rb = (p + g) * PITCH + wave * (32 * PITCH);

    f32x4 acc[8][2];
#pragma unroll
    for (int k = 0; k < 8; ++k)
#pragma unroll
      for (int r = 0; r < 2; ++r) { f32x4 z = {0.f, 0.f, 0.f, 0.f}; acc[k][r] = z; }

    short8 F[6], G[5];
#pragma unroll
    for (int u = 0; u < 6; ++u) F[u] = load_a16(wbase + 8 * u);
    G[0] = mkG(F[0], F[1]);
    G[1] = mkG(F[1], F[2]);

#pragma unroll 1
    for (int c = 0; c < 33; ++c) {
      __builtin_amdgcn_s_setprio(1);
      const int SLO[8] = {0, 0, 1, 1, 2, 2, 3, 3};
#pragma unroll
      for (int s = 0; s < 8; ++s) {
        if (s == 0) G[2] = mkG(F[2], F[3]);
        if (s == 1) G[3] = mkG(F[3], F[4]);
        if (s == 2) G[4] = mkG(F[4], F[5]);
        short8 bv0 = *(const short8*)&xt[rb + s * 8];
        short8 bv1 = *(const short8*)&xt[rb + 16 * PITCH + s * 8];
#pragma unroll
        for (int k = 0; k < 8; ++k) {
          if (s >= SLO[k] && s <= SLO[k] + 4) {
            const int idx = s - SLO[k];
            short8 a = (k & 1) ? F[idx] : G[idx];
            acc[k][0] = __builtin_amdgcn_mfma_f32_16x16x32_bf16(a, bv0, acc[k][0], 0, 0, 0);
            acc[k][1] = __builtin_amdgcn_mfma_f32_16x16x32_bf16(a, bv1, acc[k][1], 0, 0, 0);
          }
        }
        // in-place prefetch of next-c fragments (after last use this c)
        if (s >= 3) F[s - 3] = load_a16(wp + 8 * (s - 3));
        if (s == 6) G[0] = mkG(F[0], F[1]);   // next-c G
        if (s == 7) G[1] = mkG(F[1], F[2]);   // next-c G
      }
      F[5] = load_a16(wp + 40);
      __builtin_amdgcn_s_setprio(0);
      wp += 4 * D2;                // dt += 4
      rb += 4 * PITCH;             // row += 4
    }

    // ---- epilogue: modulus + avg-pool, deduped across lane halves ----
    // lo lanes (g=0,1) finish r=0,1 -> ch 4g+{0,1};
    // hi lanes (g=2,3) finish r=2,3 -> ch 4(g-2)+{2,3}.
#pragma unroll
    for (int k = 0; k < 8; ++k) {
      const int fo = f0 + gamma + 4 * k;
#pragma unroll
      for (int fr = 0; fr < 2; ++fr) {
        const int tbase = t0 + 32 * wave + 16 * fr;
        float sq[4];
#pragma unroll
        for (int r = 0; r < 4; ++r) {
          float a = acc[k][fr][r];
          float o = __shfl_xor(a, 32);
          sq[r] = a * a + o * o;
        }
        float m0 = sqrtf(hi ? sq[2] : sq[0]);
        float m1 = sqrtf(hi ? sq[3] : sq[1]);
        if (lw == 4) { m0 += __shfl_xor(m0, 8); m1 += __shfl_xor(m1, 8); }
        if (lw >= 3) { m0 += __shfl_xor(m0, 4); m1 += __shfl_xor(m1, 4); }
        if (lw >= 2) { m0 += __shfl_xor(m0, 2); m1 += __shfl_xor(m1, 2); }
        m0 += __shfl_xor(m0, 1);  m1 += __shfl_xor(m1, 1);
        if ((p & ((1 << lw) - 1)) == 0) {
          const int ch0 = 4 * (g & 1) + (hi ? 2 : 0);
          const int tcol = (tbase + p) >> lw;
          size_t o0 = (((size_t)b * 32 + oct * 8 + ch0) * 128 + fo) * 1024 + tcol;
          out[o0] = m0 * invw;
          out[o0 + (size_t)128 * 1024] = m1 * invw;   // ch0+1
        }
      }
    }
  }
}

// ---------------------------------------------------------------------------
extern "C" void kernel_launch(void* const* d_in, const int* in_sizes, int n_in,
                              void* d_out, int out_size, void* d_ws, size_t ws_size,
                              hipStream_t stream) {
  const float* x  = (const float*)d_in[0];
  const float* wr = (const float*)d_in[1];
  const float* wi = (const float*)d_in[2];
  float* out = (float*)d_out;

  ushort* xT0 = (ushort*)d_ws;                       // 4*16384*128
  ushort* xT1 = xT0 + (size_t)4 * 16384 * 128;       // 4*8192*128
  ushort* xT2 = xT1 + (size_t)4 * 8192 * 128;        // 4*4096*128
  ushort* xT3 = xT2 + (size_t)4 * 4096 * 128;        // 4*2048*128
  ushort* wq  = xT3 + (size_t)4 * 2048 * 128;        // 1671168

  prep_w<<<1671168 / 256, 256, 0, stream>>>(wr, wi, wq);
  prep_x<<<dim3(T_FULL / 64, B_), 256, 0, stream>>>(x, xT0, xT1, xT2, xT3);

  conv_mfma<<<3840, 256, 0, stream>>>(xT0, xT1, xT2, xT3, wq, out);
}